// Round 18
// baseline (106.570 us; speedup 1.0000x reference)
//
#include <hip/hip_runtime.h>
#include <hip/hip_bf16.h>

typedef float f32x4 __attribute__((ext_vector_type(4)));
typedef short bf16x8 __attribute__((ext_vector_type(8)));
typedef short s16x4 __attribute__((ext_vector_type(4)));
typedef unsigned int u32;

#define MFMA16(a, b, c) __builtin_amdgcn_mfma_f32_16x16x32_bf16((a), (b), (c), 0, 0, 0)

// pack two floats -> u32 of 2 bf16 (RNE, v_cvt_pk_bf16_f32)
__device__ __forceinline__ u32 pk2(float lo, float hi) {
    union { __hip_bfloat162 h; u32 u; } c;
    c.h = __float22bfloat162_rn(float2{lo, hi});
    return c.u;
}

// round-to-nearest-even float -> bf16 bits (helper for prep)
__device__ __forceinline__ unsigned short f2bf(float x) {
    union { float f; unsigned int u; } a; a.f = x;
    unsigned int r = a.u + 0x7fffu + ((a.u >> 16) & 1u);
    return (unsigned short)(r >> 16);
}

// ---------------------------------------------------------------------------
// prep: pack bf16 transposed weights + pre-gathered bias/mask tables into ws
//   WT  [c=384][kk=128] bf16, c = h*96 + p*32 + n   (p: 0=q,1=k,2=v)
//   WoT [f=128][e=128]  bf16  (WoT[f][e] = Wo[e][f])
//   bqkv[384] f32 (same c indexing)
//   bm  [v=4][qt=4][kt=4][lane=64][r=4] f32: (bias*log2e, -1e30 if masked)
//     for q = qt*16 + (lane&15), k = kt*16 + (lane>>4)*4 + r   (swapped layout)
// ---------------------------------------------------------------------------
__global__ void prep_kernel(const float* __restrict__ Wq, const float* __restrict__ bq,
                            const float* __restrict__ Wk, const float* __restrict__ bk,
                            const float* __restrict__ Wv, const float* __restrict__ bv,
                            const float* __restrict__ pos_bias, const float* __restrict__ Wo,
                            unsigned short* __restrict__ WT, unsigned short* __restrict__ WoT,
                            float* __restrict__ bqkv, float* __restrict__ bm) {
    const float LOG2E = 1.4426950408889634f;
    int t = blockIdx.x * blockDim.x + threadIdx.x;
    int nt = gridDim.x * blockDim.x;
    for (int i = t; i < 384 * 128; i += nt) {
        int c = i >> 7, kk = i & 127;
        int h = c / 96, rem = c - h * 96, p = rem >> 5, n = rem & 31;
        const float* W = (p == 0) ? Wq : (p == 1 ? Wk : Wv);
        WT[i] = f2bf(W[(h * 128 + kk) * 32 + n]);
    }
    for (int i = t; i < 128 * 128; i += nt) {
        int n = i >> 7, kk = i & 127;
        WoT[i] = f2bf(Wo[kk * 128 + n]);
    }
    for (int i = t; i < 384; i += nt) {
        int h = i / 96, rem = i - h * 96, p = rem >> 5, n = rem & 31;
        const float* b = (p == 0) ? bq : (p == 1 ? bk : bv);
        bqkv[i] = b[h * 32 + n];
    }
    for (int i = t; i < 4 * 4 * 4 * 64 * 4; i += nt) {
        int r = i & 3, l = (i >> 2) & 63, kt = (i >> 8) & 3, qt = (i >> 10) & 3, v = (i >> 12) & 3;
        int q = qt * 16 + (l & 15);
        int k = kt * 16 + ((l >> 4) << 2) + r;
        int qi = q >> 3, qj = q & 7, ki = k >> 3, kj = k & 7;
        bool masked = (((v >> 1) != 0) && ((qi < 4) != (ki < 4))) ||
                      (((v & 1) != 0) && ((qj < 4) != (kj < 4)));
        bm[i] = masked ? -1e30f : pos_bias[(qi - ki + 7) * 15 + (qj - kj + 7)] * LOG2E;
    }
}

// ---------------------------------------------------------------------------
// v18 = R17 (best: 105.6us — max-free softmax, per-qt attnout writeback,
// 48 KB LDS, 2 barriers, (256,3), XCD swizzle) with the P shuffle-exchange
// replaced by an LDS round-trip through the DEAD V^T region:
//   - vf is register-resident before the qt loop -> head-h's V^T space
//     (2048 shorts) is free; wave-private -> no race, no new barrier
//     (per-wave DS ops execute in order, so write-after-read is safe).
//   - per qt: 16 ds_bpermute (8 productive, 2-deep dependent chain) ->
//     4 ds_write_b64 + 2 ds_read_b128. 40 fewer DS ops/wave and the
//     serial shuffle chain leaves the hot loop.
//   - P stored at [row l15][col k ^ sw15] (XOR is a multiple of 8 shorts:
//     preserves b64/b128 alignment & in-block order); read at
//     (ks*32+l4*8)^sw15 yields P[q=l15][k=ks*32+l4*8+j] — bit-identical
//     to the shuffle version's fragment.
// LDS (48 KB, shorts):
//   [0,8192)      : xb[64][128]            (written pre-B1, read-only after)
//   [8192,16384)  : V^T[4 heads][32 n][64 tok] -> P[4 heads][16 q][64 k]
//   [16384,24576) : attnout[64][128]
// ---------------------------------------------------------------------------
__launch_bounds__(256, 3)
__global__ void swin_kernel(const float* __restrict__ patches,
                            const unsigned short* __restrict__ WT,
                            const float* __restrict__ bqkv,
                            const float* __restrict__ bm,
                            const unsigned short* __restrict__ WoT,
                            const float* __restrict__ bo,
                            float* __restrict__ out) {
    __shared__ short lds[24576];
    const int win = ((blockIdx.x & 7) << 9) | (blockIdx.x >> 3);  // XCD swizzle
    const int tid = threadIdx.x;
    const int lane = tid & 63;
    const int h = tid >> 6;
    const int l15 = lane & 15, l4 = lane >> 4;
    const int sw15 = (l15 & 7) << 3;       // swizzle for rows congruent to l15 (mod 8)
    const f32x4 zero = {0.f, 0.f, 0.f, 0.f};
    const int sA = ((l4 & 1) << 5) + l15;  // exchange src lane, words 0,1
    const int sB = sA + 16;                //                    words 2,3
    const float rs2 = 0.2550348660629988f; // log2(e)/sqrt(32)
    const float4* bmv = reinterpret_cast<const float4*>(bm);
    const int mv = (((win >> 4) & 15) == 15 ? 2 : 0) + ((win & 15) == 15 ? 1 : 0);

    // ---- stage 1: patches (f32) -> xb (bf16, swizzled) ----
    {
        const float4* src = reinterpret_cast<const float4*>(patches + (size_t)win * 8192);
        #pragma unroll
        for (int i = 0; i < 8; ++i) {
            int idx4 = i * 256 + tid;
            float4 v = src[idx4];
            int row = idx4 >> 5, col = (idx4 & 31) << 2;
            union { u32 u[2]; s16x4 s; } pk;
            pk.u[0] = pk2(v.x, v.y);
            pk.u[1] = pk2(v.z, v.w);
            *reinterpret_cast<s16x4*>(&lds[row * 128 + (col ^ ((row & 7) << 3))]) = pk.s;
        }
    }
    __syncthreads();  // B1: xb ready

    // ---- stage 2a: x fragments (all waves read all of xb) ----
    bf16x8 xa[4][4];
    #pragma unroll
    for (int mt = 0; mt < 4; ++mt)
        #pragma unroll
        for (int ks = 0; ks < 4; ++ks)
            xa[mt][ks] = *reinterpret_cast<const bf16x8*>(
                &lds[(mt * 16 + l15) * 128 + ((ks * 32 + l4 * 8) ^ sw15)]);
    // no barrier needed: V^T has its own region; xb is never rewritten

    // ---- stage 2b: Q,K projection (SWAPPED mfma(W,X)); C-out -> shfl-exchange
    //      directly into QK^T fragments (no LDS). ct 0,1 = Q; ct 2,3 = K. ----
    bf16x8 qf[4], kf[4];
    #pragma unroll
    for (int ct = 0; ct < 4; ++ct) {
        bf16x8 wb[4];
        #pragma unroll
        for (int ks = 0; ks < 4; ++ks)
            wb[ks] = *reinterpret_cast<const bf16x8*>(
                &WT[(h * 96 + ct * 16 + l15) * 128 + ks * 32 + l4 * 8]);
        float b4[4];
        #pragma unroll
        for (int r = 0; r < 4; ++r) b4[r] = bqkv[h * 96 + ct * 16 + l4 * 4 + r];
        #pragma unroll
        for (int mt = 0; mt < 4; ++mt) {
            f32x4 a = zero;
            __builtin_amdgcn_s_setprio(1);
            #pragma unroll
            for (int ks = 0; ks < 4; ++ks) a = MFMA16(wb[ks], xa[mt][ks], a);
            __builtin_amdgcn_s_setprio(0);
            u32 pw0 = pk2(a[0] + b4[0], a[1] + b4[1]);
            u32 pw1 = pk2(a[2] + b4[2], a[3] + b4[3]);
            u32 e0 = __shfl(pw0, sA);
            u32 e1 = __shfl(pw1, sA);
            u32 e2 = __shfl(pw0, sB);
            u32 e3 = __shfl(pw1, sB);
            if ((ct & 1) == (l4 >> 1)) {  // this lane's fragment comes from this ct
                union { u32 u[4]; bf16x8 v; } c;
                c.u[0] = e0; c.u[1] = e1; c.u[2] = e2; c.u[3] = e3;
                if (ct < 2) qf[mt] = c.v; else kf[mt] = c.v;
            }
        }
    }

    // ---- stage 2c: V projection (normal mfma(X,W)) -> V^T region, b64 writes
    #pragma unroll
    for (int ctv = 0; ctv < 2; ++ctv) {
        bf16x8 wb[4];
        #pragma unroll
        for (int ks = 0; ks < 4; ++ks)
            wb[ks] = *reinterpret_cast<const bf16x8*>(
                &WT[(h * 96 + 64 + ctv * 16 + l15) * 128 + ks * 32 + l4 * 8]);
        float bb = bqkv[h * 96 + 64 + ctv * 16 + l15];
        __builtin_amdgcn_s_setprio(1);
        #pragma unroll
        for (int mt = 0; mt < 4; ++mt) {
            f32x4 a = zero;
            #pragma unroll
            for (int ks = 0; ks < 4; ++ks) a = MFMA16(xa[mt][ks], wb[ks], a);
            int n = ctv * 16 + l15;
            int tok0 = (mt * 16 + l4 * 4) ^ sw15;  // n&7 == l15&7
            union { u32 u[2]; s16x4 s; } pk;
            pk.u[0] = pk2(a[0] + bb, a[1] + bb);
            pk.u[1] = pk2(a[2] + bb, a[3] + bb);
            *reinterpret_cast<s16x4*>(&lds[8192 + h * 2048 + n * 64 + tok0]) = pk.s;
        }
        __builtin_amdgcn_s_setprio(0);
    }

    // ---- stage 3+4 (wave-local, barrier-free): swapped QK^T, max-free
    //      softmax, P via LDS (dead V^T space), swapped PV; per-qt attnout ----
    bf16x8 vf[2][2];
    #pragma unroll
    for (int nt = 0; nt < 2; ++nt)
        #pragma unroll
        for (int ks = 0; ks < 2; ++ks)
            vf[nt][ks] = *reinterpret_cast<const bf16x8*>(
                &lds[8192 + h * 2048 + (nt * 16 + l15) * 64 + ((ks * 32 + l4 * 8) ^ sw15)]);
    // after these reads head-h's V^T space is dead -> reuse as P[16 q][64 k]
    short* Pb = &lds[8192 + h * 2048 + l15 * 64];

    float4 bcur[4], bnxt[4];
    #pragma unroll
    for (int kt = 0; kt < 4; ++kt) bcur[kt] = bmv[((mv * 4 + 0) * 4 + kt) * 64 + lane];

    #pragma unroll
    for (int qt = 0; qt < 4; ++qt) {
        f32x4 LT[4];
        __builtin_amdgcn_s_setprio(1);
        #pragma unroll
        for (int kt = 0; kt < 4; ++kt) LT[kt] = MFMA16(kf[kt], qf[qt], zero);
        __builtin_amdgcn_s_setprio(0);

        if (qt < 3) {  // prefetch next qt's bias/mask under this qt's softmax
            #pragma unroll
            for (int kt = 0; kt < 4; ++kt)
                bnxt[kt] = bmv[((mv * 4 + qt + 1) * 4 + kt) * 64 + lane];
        }

        // lane holds S[q=qt*16+l15][k=kt*16+l4*4+r]; exp2 directly (bounded)
        float s = 0.f;
        float x[4][4];
        #pragma unroll
        for (int kt = 0; kt < 4; ++kt) {
            x[kt][0] = exp2f(LT[kt][0] * rs2 + bcur[kt].x);
            x[kt][1] = exp2f(LT[kt][1] * rs2 + bcur[kt].y);
            x[kt][2] = exp2f(LT[kt][2] * rs2 + bcur[kt].z);
            x[kt][3] = exp2f(LT[kt][3] * rs2 + bcur[kt].w);
            s += (x[kt][0] + x[kt][1]) + (x[kt][2] + x[kt][3]);
        }
        s += __shfl_xor(s, 16);
        s += __shfl_xor(s, 32);
        float inv = 1.0f / s;

        // P -> LDS: lane writes P[q=l15][k=kt*16+l4*4 .. +3] at col k^sw15
        #pragma unroll
        for (int kt = 0; kt < 4; ++kt) {
            union { u32 u[2]; s16x4 s4; } pw;
            pw.u[0] = pk2(x[kt][0] * inv, x[kt][1] * inv);
            pw.u[1] = pk2(x[kt][2] * inv, x[kt][3] * inv);
            *reinterpret_cast<s16x4*>(&Pb[(kt * 16 + l4 * 4) ^ sw15]) = pw.s4;
        }
        // P fragments: lane reads P[q=l15][k=ks*32+l4*8 .. +7]
        bf16x8 pf0 = *reinterpret_cast<const bf16x8*>(&Pb[(l4 * 8) ^ sw15]);
        bf16x8 pf1 = *reinterpret_cast<const bf16x8*>(&Pb[(32 + l4 * 8) ^ sw15]);

        f32x4 O0 = zero, O1 = zero;
        __builtin_amdgcn_s_setprio(1);
        O0 = MFMA16(vf[0][0], pf0, O0);
        O0 = MFMA16(vf[0][1], pf1, O0);
        O1 = MFMA16(vf[1][0], pf0, O1);
        O1 = MFMA16(vf[1][1], pf1, O1);
        __builtin_amdgcn_s_setprio(0);

        // attnout chunk for this qt -> LDS immediately (frees the accumulator)
        {
            int q = qt * 16 + l15;
            union { u32 u[2]; s16x4 s4; } pk;
            pk.u[0] = pk2(O0[0], O0[1]);
            pk.u[1] = pk2(O0[2], O0[3]);
            *reinterpret_cast<s16x4*>(
                &lds[16384 + q * 128 + ((h * 32 + l4 * 4) ^ sw15)]) = pk.s4;
            pk.u[0] = pk2(O1[0], O1[1]);
            pk.u[1] = pk2(O1[2], O1[3]);
            *reinterpret_cast<s16x4*>(
                &lds[16384 + q * 128 + ((h * 32 + 16 + l4 * 4) ^ sw15)]) = pk.s4;
        }

        if (qt < 3) {
            #pragma unroll
            for (int kt = 0; kt < 4; ++kt) bcur[kt] = bnxt[kt];
        }
    }

    // ---- stage 5 weight loads issued before the barrier (hide latency) ----
    bf16x8 wf[2][4];
    #pragma unroll
    for (int nt = 0; nt < 2; ++nt)
        #pragma unroll
        for (int ks = 0; ks < 4; ++ks)
            wf[nt][ks] = *reinterpret_cast<const bf16x8*>(
                &WoT[(h * 32 + nt * 16 + l15) * 128 + ks * 32 + l4 * 8]);
    float4 bo4[2];
    #pragma unroll
    for (int nt = 0; nt < 2; ++nt)
        bo4[nt] = *reinterpret_cast<const float4*>(&bo[h * 32 + nt * 16 + l4 * 4]);

    __syncthreads();  // B2: attnout published across heads

    // ---- stage 5: out = attnout @ Wo + bo (SWAPPED -> float4 stores) ----
    {
        float* outw = out + (size_t)win * 8192;
        #pragma unroll
        for (int mt = 0; mt < 4; ++mt) {
            bf16x8 af[4];
            #pragma unroll
            for (int ks = 0; ks < 4; ++ks)
                af[ks] = *reinterpret_cast<const bf16x8*>(
                    &lds[16384 + (mt * 16 + l15) * 128 + ((ks * 32 + l4 * 8) ^ sw15)]);
            __builtin_amdgcn_s_setprio(1);
            #pragma unroll
            for (int nt = 0; nt < 2; ++nt) {
                f32x4 a = zero;
                #pragma unroll
                for (int ks = 0; ks < 4; ++ks) a = MFMA16(wf[nt][ks], af[ks], a);
                float4 st;
                st.x = a[0] + bo4[nt].x;
                st.y = a[1] + bo4[nt].y;
                st.z = a[2] + bo4[nt].z;
                st.w = a[3] + bo4[nt].w;
                *reinterpret_cast<float4*>(
                    &outw[(size_t)(mt * 16 + l15) * 128 + h * 32 + nt * 16 + l4 * 4]) = st;
            }
            __builtin_amdgcn_s_setprio(0);
        }
    }
}

extern "C" void kernel_launch(void* const* d_in, const int* in_sizes, int n_in,
                              void* d_out, int out_size, void* d_ws, size_t ws_size,
                              hipStream_t stream) {
    const float* patches  = (const float*)d_in[0];
    const float* Wq       = (const float*)d_in[1];
    const float* bq       = (const float*)d_in[2];
    const float* Wk       = (const float*)d_in[3];
    const float* bk       = (const float*)d_in[4];
    const float* Wv       = (const float*)d_in[5];
    const float* bv       = (const float*)d_in[6];
    const float* pos_bias = (const float*)d_in[7];
    const float* Wo       = (const float*)d_in[8];
    const float* bo       = (const float*)d_in[9];
    // d_in[10] (mask) is recomputed analytically in prep_kernel.

    char* ws = (char*)d_ws;
    unsigned short* WT  = (unsigned short*)(ws);            // 98304 B
    unsigned short* WoT = (unsigned short*)(ws + 98304);    // 32768 B
    float* bqkv         = (float*)(ws + 131072);            // 1536 B
    float* bm           = (float*)(ws + 132608);            // 65536 B (16B-aligned)

    hipLaunchKernelGGL(prep_kernel, dim3(64), dim3(256), 0, stream,
                       Wq, bq, Wk, bk, Wv, bv, pos_bias, Wo, WT, WoT, bqkv, bm);
    hipLaunchKernelGGL(swin_kernel, dim3(4096), dim3(256), 0, stream,
                       patches, WT, bqkv, bm, WoT, bo, (float*)d_out);
}

// Round 19
// 103.271 us; speedup vs baseline: 1.0319x; 1.0319x over previous
//
#include <hip/hip_runtime.h>
#include <hip/hip_bf16.h>

typedef float f32x4 __attribute__((ext_vector_type(4)));
typedef short bf16x8 __attribute__((ext_vector_type(8)));
typedef short s16x4 __attribute__((ext_vector_type(4)));
typedef unsigned int u32;

#define MFMA16(a, b, c) __builtin_amdgcn_mfma_f32_16x16x32_bf16((a), (b), (c), 0, 0, 0)

// pack two floats -> u32 of 2 bf16 (RNE, v_cvt_pk_bf16_f32)
__device__ __forceinline__ u32 pk2(float lo, float hi) {
    union { __hip_bfloat162 h; u32 u; } c;
    c.h = __float22bfloat162_rn(float2{lo, hi});
    return c.u;
}

// round-to-nearest-even float -> bf16 bits (helper for prep)
__device__ __forceinline__ unsigned short f2bf(float x) {
    union { float f; unsigned int u; } a; a.f = x;
    unsigned int r = a.u + 0x7fffu + ((a.u >> 16) & 1u);
    return (unsigned short)(r >> 16);
}

// ---------------------------------------------------------------------------
// prep: pack bf16 transposed weights + pre-gathered bias/mask tables into ws
//   WT  [c=384][kk=128] bf16, c = h*96 + p*32 + n   (p: 0=q,1=k,2=v)
//   WoT [f=128][e=128]  bf16  (WoT[f][e] = Wo[e][f])
//   bqkv[384] f32 (same c indexing)
//   bm  [v=4][qt=4][kt=4][lane=64][r=4] f32: (bias*log2e, -1e30 if masked)
//     for q = qt*16 + (lane&15), k = kt*16 + (lane>>4)*4 + r   (swapped layout)
// ---------------------------------------------------------------------------
__global__ void prep_kernel(const float* __restrict__ Wq, const float* __restrict__ bq,
                            const float* __restrict__ Wk, const float* __restrict__ bk,
                            const float* __restrict__ Wv, const float* __restrict__ bv,
                            const float* __restrict__ pos_bias, const float* __restrict__ Wo,
                            unsigned short* __restrict__ WT, unsigned short* __restrict__ WoT,
                            float* __restrict__ bqkv, float* __restrict__ bm) {
    const float LOG2E = 1.4426950408889634f;
    int t = blockIdx.x * blockDim.x + threadIdx.x;
    int nt = gridDim.x * blockDim.x;
    for (int i = t; i < 384 * 128; i += nt) {
        int c = i >> 7, kk = i & 127;
        int h = c / 96, rem = c - h * 96, p = rem >> 5, n = rem & 31;
        const float* W = (p == 0) ? Wq : (p == 1 ? Wk : Wv);
        WT[i] = f2bf(W[(h * 128 + kk) * 32 + n]);
    }
    for (int i = t; i < 128 * 128; i += nt) {
        int n = i >> 7, kk = i & 127;
        WoT[i] = f2bf(Wo[kk * 128 + n]);
    }
    for (int i = t; i < 384; i += nt) {
        int h = i / 96, rem = i - h * 96, p = rem >> 5, n = rem & 31;
        const float* b = (p == 0) ? bq : (p == 1 ? bk : bv);
        bqkv[i] = b[h * 32 + n];
    }
    for (int i = t; i < 4 * 4 * 4 * 64 * 4; i += nt) {
        int r = i & 3, l = (i >> 2) & 63, kt = (i >> 8) & 3, qt = (i >> 10) & 3, v = (i >> 12) & 3;
        int q = qt * 16 + (l & 15);
        int k = kt * 16 + ((l >> 4) << 2) + r;
        int qi = q >> 3, qj = q & 7, ki = k >> 3, kj = k & 7;
        bool masked = (((v >> 1) != 0) && ((qi < 4) != (ki < 4))) ||
                      (((v & 1) != 0) && ((qj < 4) != (kj < 4)));
        bm[i] = masked ? -1e30f : pos_bias[(qi - ki + 7) * 15 + (qj - kj + 7)] * LOG2E;
    }
}

// ---------------------------------------------------------------------------
// v19 = R17 EXACTLY (best: 105.6us — max-free softmax, per-qt attnout
// writeback, shfl P-exchange, 48 KB LDS, 2 barriers, (256,3), XCD swizzle)
// with ALL s_setprio toggles REMOVED — single-variable A/B:
//   m191: setprio +4-7% on attn with independent 1-wave blocks;
//   m190: setprio −14TF on 4-wave lockstep GEMM.
// Ours is 4-wave barrier-synced blocks with ~40 toggle pairs (~80 SALU ops)
// wrapping tiny MFMA clusters and NO phase-diverse wave roles (T5's
// prerequisite, m218b) -> the m190 branch (neutral-to-harmful) is the prior.
// If |delta| < 3%: practical plateau; write up the structural constraint.
// LDS (48 KB, shorts):
//   [0,8192)      : xb[64][128]            (written pre-B1, read-only after)
//   [8192,16384)  : V^T[4 heads][32 n][64 tok]  (wave-private)
//   [16384,24576) : attnout[64][128]
// ---------------------------------------------------------------------------
__launch_bounds__(256, 3)
__global__ void swin_kernel(const float* __restrict__ patches,
                            const unsigned short* __restrict__ WT,
                            const float* __restrict__ bqkv,
                            const float* __restrict__ bm,
                            const unsigned short* __restrict__ WoT,
                            const float* __restrict__ bo,
                            float* __restrict__ out) {
    __shared__ short lds[24576];
    const int win = ((blockIdx.x & 7) << 9) | (blockIdx.x >> 3);  // XCD swizzle
    const int tid = threadIdx.x;
    const int lane = tid & 63;
    const int h = tid >> 6;
    const int l15 = lane & 15, l4 = lane >> 4;
    const int sw15 = (l15 & 7) << 3;       // swizzle for rows congruent to l15 (mod 8)
    const f32x4 zero = {0.f, 0.f, 0.f, 0.f};
    const int sA = ((l4 & 1) << 5) + l15;  // exchange src lane, words 0,1
    const int sB = sA + 16;                //                    words 2,3
    const float rs2 = 0.2550348660629988f; // log2(e)/sqrt(32)
    const float4* bmv = reinterpret_cast<const float4*>(bm);
    const int mv = (((win >> 4) & 15) == 15 ? 2 : 0) + ((win & 15) == 15 ? 1 : 0);

    // ---- stage 1: patches (f32) -> xb (bf16, swizzled) ----
    {
        const float4* src = reinterpret_cast<const float4*>(patches + (size_t)win * 8192);
        #pragma unroll
        for (int i = 0; i < 8; ++i) {
            int idx4 = i * 256 + tid;
            float4 v = src[idx4];
            int row = idx4 >> 5, col = (idx4 & 31) << 2;
            union { u32 u[2]; s16x4 s; } pk;
            pk.u[0] = pk2(v.x, v.y);
            pk.u[1] = pk2(v.z, v.w);
            *reinterpret_cast<s16x4*>(&lds[row * 128 + (col ^ ((row & 7) << 3))]) = pk.s;
        }
    }
    __syncthreads();  // B1: xb ready

    // ---- stage 2a: x fragments (all waves read all of xb) ----
    bf16x8 xa[4][4];
    #pragma unroll
    for (int mt = 0; mt < 4; ++mt)
        #pragma unroll
        for (int ks = 0; ks < 4; ++ks)
            xa[mt][ks] = *reinterpret_cast<const bf16x8*>(
                &lds[(mt * 16 + l15) * 128 + ((ks * 32 + l4 * 8) ^ sw15)]);
    // no barrier needed: V^T has its own region; xb is never rewritten

    // ---- stage 2b: Q,K projection (SWAPPED mfma(W,X)); C-out -> shfl-exchange
    //      directly into QK^T fragments (no LDS). ct 0,1 = Q; ct 2,3 = K. ----
    bf16x8 qf[4], kf[4];
    #pragma unroll
    for (int ct = 0; ct < 4; ++ct) {
        bf16x8 wb[4];
        #pragma unroll
        for (int ks = 0; ks < 4; ++ks)
            wb[ks] = *reinterpret_cast<const bf16x8*>(
                &WT[(h * 96 + ct * 16 + l15) * 128 + ks * 32 + l4 * 8]);
        float b4[4];
        #pragma unroll
        for (int r = 0; r < 4; ++r) b4[r] = bqkv[h * 96 + ct * 16 + l4 * 4 + r];
        #pragma unroll
        for (int mt = 0; mt < 4; ++mt) {
            f32x4 a = zero;
            #pragma unroll
            for (int ks = 0; ks < 4; ++ks) a = MFMA16(wb[ks], xa[mt][ks], a);
            u32 pw0 = pk2(a[0] + b4[0], a[1] + b4[1]);
            u32 pw1 = pk2(a[2] + b4[2], a[3] + b4[3]);
            u32 e0 = __shfl(pw0, sA);
            u32 e1 = __shfl(pw1, sA);
            u32 e2 = __shfl(pw0, sB);
            u32 e3 = __shfl(pw1, sB);
            if ((ct & 1) == (l4 >> 1)) {  // this lane's fragment comes from this ct
                union { u32 u[4]; bf16x8 v; } c;
                c.u[0] = e0; c.u[1] = e1; c.u[2] = e2; c.u[3] = e3;
                if (ct < 2) qf[mt] = c.v; else kf[mt] = c.v;
            }
        }
    }

    // ---- stage 2c: V projection (normal mfma(X,W)) -> V^T region, b64 writes
    #pragma unroll
    for (int ctv = 0; ctv < 2; ++ctv) {
        bf16x8 wb[4];
        #pragma unroll
        for (int ks = 0; ks < 4; ++ks)
            wb[ks] = *reinterpret_cast<const bf16x8*>(
                &WT[(h * 96 + 64 + ctv * 16 + l15) * 128 + ks * 32 + l4 * 8]);
        float bb = bqkv[h * 96 + 64 + ctv * 16 + l15];
        #pragma unroll
        for (int mt = 0; mt < 4; ++mt) {
            f32x4 a = zero;
            #pragma unroll
            for (int ks = 0; ks < 4; ++ks) a = MFMA16(xa[mt][ks], wb[ks], a);
            int n = ctv * 16 + l15;
            int tok0 = (mt * 16 + l4 * 4) ^ sw15;  // n&7 == l15&7
            union { u32 u[2]; s16x4 s; } pk;
            pk.u[0] = pk2(a[0] + bb, a[1] + bb);
            pk.u[1] = pk2(a[2] + bb, a[3] + bb);
            *reinterpret_cast<s16x4*>(&lds[8192 + h * 2048 + n * 64 + tok0]) = pk.s;
        }
    }

    // ---- stage 3+4 (wave-local, barrier-free): swapped QK^T, max-free
    //      softmax, shfl-built P fragments, swapped PV; per-qt attnout ----
    bf16x8 vf[2][2];
    #pragma unroll
    for (int nt = 0; nt < 2; ++nt)
        #pragma unroll
        for (int ks = 0; ks < 2; ++ks)
            vf[nt][ks] = *reinterpret_cast<const bf16x8*>(
                &lds[8192 + h * 2048 + (nt * 16 + l15) * 64 + ((ks * 32 + l4 * 8) ^ sw15)]);

    float4 bcur[4], bnxt[4];
    #pragma unroll
    for (int kt = 0; kt < 4; ++kt) bcur[kt] = bmv[((mv * 4 + 0) * 4 + kt) * 64 + lane];

    #pragma unroll
    for (int qt = 0; qt < 4; ++qt) {
        f32x4 LT[4];
        #pragma unroll
        for (int kt = 0; kt < 4; ++kt) LT[kt] = MFMA16(kf[kt], qf[qt], zero);

        if (qt < 3) {  // prefetch next qt's bias/mask under this qt's softmax
            #pragma unroll
            for (int kt = 0; kt < 4; ++kt)
                bnxt[kt] = bmv[((mv * 4 + qt + 1) * 4 + kt) * 64 + lane];
        }

        // lane holds S[q=qt*16+l15][k=kt*16+l4*4+r]; exp2 directly (bounded)
        float s = 0.f;
        float x[4][4];
        #pragma unroll
        for (int kt = 0; kt < 4; ++kt) {
            x[kt][0] = exp2f(LT[kt][0] * rs2 + bcur[kt].x);
            x[kt][1] = exp2f(LT[kt][1] * rs2 + bcur[kt].y);
            x[kt][2] = exp2f(LT[kt][2] * rs2 + bcur[kt].z);
            x[kt][3] = exp2f(LT[kt][3] * rs2 + bcur[kt].w);
            s += (x[kt][0] + x[kt][1]) + (x[kt][2] + x[kt][3]);
        }
        s += __shfl_xor(s, 16);
        s += __shfl_xor(s, 32);
        float inv = 1.0f / s;

        u32 wp[4][2];
        #pragma unroll
        for (int kt = 0; kt < 4; ++kt) {
            wp[kt][0] = pk2(x[kt][0] * inv, x[kt][1] * inv);
            wp[kt][1] = pk2(x[kt][2] * inv, x[kt][3] * inv);
        }
        // exchange -> B-frag of PV: lane needs P[q=l15][k=ks*32+l4*8+j]
        u32 fr[2][4];
        #pragma unroll
        for (int kt = 0; kt < 4; ++kt) {
            u32 a0 = __shfl(wp[kt][0], sA);
            u32 a1 = __shfl(wp[kt][1], sA);
            u32 b0 = __shfl(wp[kt][0], sB);
            u32 b1 = __shfl(wp[kt][1], sB);
            if ((kt & 1) == (l4 >> 1)) {
                const int ks = kt >> 1;
                fr[ks][0] = a0; fr[ks][1] = a1; fr[ks][2] = b0; fr[ks][3] = b1;
            }
        }
        bf16x8 pf0, pf1;
        {
            union { u32 u[4]; bf16x8 v; } c0, c1;
            c0.u[0] = fr[0][0]; c0.u[1] = fr[0][1]; c0.u[2] = fr[0][2]; c0.u[3] = fr[0][3];
            c1.u[0] = fr[1][0]; c1.u[1] = fr[1][1]; c1.u[2] = fr[1][2]; c1.u[3] = fr[1][3];
            pf0 = c0.v; pf1 = c1.v;
        }
        f32x4 O0 = zero, O1 = zero;
        O0 = MFMA16(vf[0][0], pf0, O0);
        O0 = MFMA16(vf[0][1], pf1, O0);
        O1 = MFMA16(vf[1][0], pf0, O1);
        O1 = MFMA16(vf[1][1], pf1, O1);

        // attnout chunk for this qt -> LDS immediately (frees the accumulator)
        {
            int q = qt * 16 + l15;
            union { u32 u[2]; s16x4 s4; } pk;
            pk.u[0] = pk2(O0[0], O0[1]);
            pk.u[1] = pk2(O0[2], O0[3]);
            *reinterpret_cast<s16x4*>(
                &lds[16384 + q * 128 + ((h * 32 + l4 * 4) ^ sw15)]) = pk.s4;
            pk.u[0] = pk2(O1[0], O1[1]);
            pk.u[1] = pk2(O1[2], O1[3]);
            *reinterpret_cast<s16x4*>(
                &lds[16384 + q * 128 + ((h * 32 + 16 + l4 * 4) ^ sw15)]) = pk.s4;
        }

        if (qt < 3) {
            #pragma unroll
            for (int kt = 0; kt < 4; ++kt) bcur[kt] = bnxt[kt];
        }
    }

    // ---- stage 5 weight loads issued before the barrier (hide latency) ----
    bf16x8 wf[2][4];
    #pragma unroll
    for (int nt = 0; nt < 2; ++nt)
        #pragma unroll
        for (int ks = 0; ks < 4; ++ks)
            wf[nt][ks] = *reinterpret_cast<const bf16x8*>(
                &WoT[(h * 32 + nt * 16 + l15) * 128 + ks * 32 + l4 * 8]);
    float4 bo4[2];
    #pragma unroll
    for (int nt = 0; nt < 2; ++nt)
        bo4[nt] = *reinterpret_cast<const float4*>(&bo[h * 32 + nt * 16 + l4 * 4]);

    __syncthreads();  // B2: attnout published across heads

    // ---- stage 5: out = attnout @ Wo + bo (SWAPPED -> float4 stores) ----
    {
        float* outw = out + (size_t)win * 8192;
        #pragma unroll
        for (int mt = 0; mt < 4; ++mt) {
            bf16x8 af[4];
            #pragma unroll
            for (int ks = 0; ks < 4; ++ks)
                af[ks] = *reinterpret_cast<const bf16x8*>(
                    &lds[16384 + (mt * 16 + l15) * 128 + ((ks * 32 + l4 * 8) ^ sw15)]);
            #pragma unroll
            for (int nt = 0; nt < 2; ++nt) {
                f32x4 a = zero;
                #pragma unroll
                for (int ks = 0; ks < 4; ++ks) a = MFMA16(wf[nt][ks], af[ks], a);
                float4 st;
                st.x = a[0] + bo4[nt].x;
                st.y = a[1] + bo4[nt].y;
                st.z = a[2] + bo4[nt].z;
                st.w = a[3] + bo4[nt].w;
                *reinterpret_cast<float4*>(
                    &outw[(size_t)(mt * 16 + l15) * 128 + h * 32 + nt * 16 + l4 * 4]) = st;
            }
        }
    }
}

extern "C" void kernel_launch(void* const* d_in, const int* in_sizes, int n_in,
                              void* d_out, int out_size, void* d_ws, size_t ws_size,
                              hipStream_t stream) {
    const float* patches  = (const float*)d_in[0];
    const float* Wq       = (const float*)d_in[1];
    const float* bq       = (const float*)d_in[2];
    const float* Wk       = (const float*)d_in[3];
    const float* bk       = (const float*)d_in[4];
    const float* Wv       = (const float*)d_in[5];
    const float* bv       = (const float*)d_in[6];
    const float* pos_bias = (const float*)d_in[7];
    const float* Wo       = (const float*)d_in[8];
    const float* bo       = (const float*)d_in[9];
    // d_in[10] (mask) is recomputed analytically in prep_kernel.

    char* ws = (char*)d_ws;
    unsigned short* WT  = (unsigned short*)(ws);            // 98304 B
    unsigned short* WoT = (unsigned short*)(ws + 98304);    // 32768 B
    float* bqkv         = (float*)(ws + 131072);            // 1536 B
    float* bm           = (float*)(ws + 132608);            // 65536 B (16B-aligned)

    hipLaunchKernelGGL(prep_kernel, dim3(64), dim3(256), 0, stream,
                       Wq, bq, Wk, bk, Wv, bv, pos_bias, Wo, WT, WoT, bqkv, bm);
    hipLaunchKernelGGL(swin_kernel, dim3(4096), dim3(256), 0, stream,
                       patches, WT, bqkv, bm, WoT, bo, (float*)d_out);
}